// Round 2
// baseline (303.058 us; speedup 1.0000x reference)
//
#include <hip/hip_runtime.h>
#include <hip/hip_bf16.h>

typedef __bf16 v8bf __attribute__((ext_vector_type(8)));
typedef float v4f __attribute__((ext_vector_type(4)));

#define GBL_AS(p) ((const __attribute__((address_space(1))) unsigned int*)(p))
#define LDS_AS(p) ((__attribute__((address_space(3))) unsigned int*)(p))

// s_waitcnt immediates: lgkmcnt=15 (no wait) bits[11:8], expcnt=7 bits[6:4],
// vmcnt low bits[3:0].
#define WAIT_VM6() __builtin_amdgcn_s_waitcnt(0x0F76)  // vmcnt(6)
#define WAIT_VM0() __builtin_amdgcn_s_waitcnt(0x0F70)  // vmcnt(0)
#define BAR() __builtin_amdgcn_s_barrier()

// ---------------- fp32 -> bf16 cast (x) ----------------
__global__ void cast_f32_bf16(const float* __restrict__ src,
                              __hip_bfloat16* __restrict__ dst, int n) {
  int i = (blockIdx.x * 256 + threadIdx.x) * 4;
  if (i >= n) return;
  float4 f = *(const float4*)(src + i);
  union { __hip_bfloat16 h[4]; uint2 u; } pk;
  pk.h[0] = __float2bfloat16(f.x);
  pk.h[1] = __float2bfloat16(f.y);
  pk.h[2] = __float2bfloat16(f.z);
  pk.h[3] = __float2bfloat16(f.w);
  *(uint2*)(dst + i) = pk.u;
}

// ---------------- fp32 -> bf16 cast, 3 weight tensors ----------------
__global__ void cast_w3(const float* __restrict__ a, const float* __restrict__ b,
                        const float* __restrict__ c, __hip_bfloat16* __restrict__ dst) {
  int seg = blockIdx.x >> 10;
  const float* src = seg == 0 ? a : (seg == 1 ? b : c);
  int i = ((blockIdx.x & 1023) * 256 + threadIdx.x) * 4;
  float4 f = *(const float4*)(src + i);
  union { __hip_bfloat16 h[4]; uint2 u; } pk;
  pk.h[0] = __float2bfloat16(f.x);
  pk.h[1] = __float2bfloat16(f.y);
  pk.h[2] = __float2bfloat16(f.z);
  pk.h[3] = __float2bfloat16(f.w);
  *(uint2*)(dst + seg * 1048576 + i) = pk.u;
}

// ---------------- 256x256 8-phase NT GEMM (T2+T3+T4+T5) ----------------
// 512 threads = 8 waves as 2(M) x 4(N); wave tile 128x64 = 8x4 fragments of
// 16x16; BK=64 (2 mfma-K halves); LDS = 2 x (A 256x64 + B 256x64) bf16 = 128KB
// -> 1 block/CU, grids sized so every CU gets whole blocks (no partial packing).
//
// Swizzle (T2): tile row stride is 128B (full bank stripe). 16B chunk (row r,
// col-chunk c, c in 0..7) lives at slot c ^ (r&7). Staging DMA writes linearly
// (1 quarter-tile = 64 rows x 64K = 1 dwordx4 per thread); the swizzle is
// realized by permuting each lane's GLOBAL source chunk within its 128B row
// (coalescing preserved). Reads apply the same XOR.
//
// Schedule (T3+T4), per K-tile t (buffer b = t&1), derived retire analysis:
//   P1: stage Aq1,Aq3(t+1)->buf b^1 [safe: retired P4(t-1)]; read A[0:4],B[0:4]
//       k-half0; BAR; prio1; 16 MFMA; prio0; BAR
//   P2: read A[4:8] h0; BAR; 16 MFMA; BAR
//   P3: read A[0:4],B[0:4] h1; BAR; 16 MFMA; BAR
//   P4: stage B q0..3 + A q0,q2 (t+2)->buf b [safe: retired P3(t)]; read
//       A[4:8] h1; vmcnt(6) [14 outstanding -> oldest 8 = ALL of t+1 done];
//       BAR; 16 MFMA; BAR
// vmcnt never drains to 0 except the last two iterations (T4). T5: setprio(1)
// around each MFMA cluster.
// MODE 0: proj (K=1024). z<2 -> bf16 qkv; z==2 -> transposed vT.
// MODE 1: scores->P (K=1024), triangular 256-grid, exp + fused row-sum atomics.
// MODE 2: PV, split-K (rows with K>1024 use 2 segments + fp32 atomicAdd into
//         pre-zeroed out, scaled by 1/rowsum).
template<int MODE>
__device__ static __forceinline__
void gemm8_body(const __hip_bfloat16* __restrict__ A, long sAb, int lda,
                const __hip_bfloat16* __restrict__ B, long sBb, int ldb,
                void* __restrict__ Cv, long sCb, int ldc,
                float scale, float* __restrict__ sums,
                __hip_bfloat16* __restrict__ vTp) {
  const int tid = threadIdx.x;
  const int l = tid & 63, w = tid >> 6;
  const int wr = w >> 2, wc = w & 3;

  int z, mb, nb, k0 = 0, NT;
  bool atom = false;
  if (MODE == 0) {
    const int id = blockIdx.x;                 // 384 = 3z * 32mt * 4nt
    z = id >> 7; mb = ((id >> 2) & 31) << 8; nb = (id & 3) << 8;
    NT = 16;
  } else if (MODE == 1) {
    const int id = blockIdx.x;                 // 144 = 4z * 36 triangular
    z = id / 36;
    const int t = id - z * 36;
    int m = (int)((__builtin_sqrtf(8.0f * t + 1.0f) - 1.0f) * 0.5f);
    while ((m + 1) * (m + 2) / 2 <= t) ++m;
    while (m * (m + 1) / 2 > t) --m;
    mb = m << 8; nb = (t - m * (m + 1) / 2) << 8;
    NT = 16;
  } else {
    const int id = blockIdx.x;                 // 192 = 4z * 4col * 12 segs
    z = id / 48;
    const int r48 = id - z * 48;
    const int c = r48 / 12, s = r48 - c * 12;
    nb = c << 8;
    int i, seg;
    if (s < 4) { i = s; seg = 0; }
    else       { i = 4 + ((s - 4) >> 1); seg = (s - 4) & 1; }
    mb = i << 8;
    k0 = seg ? 1024 : 0;
    const int k1 = seg ? ((i + 1) << 8) : ((i < 4) ? ((i + 1) << 8) : 1024);
    NT = (k1 - k0) >> 6;
    atom = (i >= 4);
  }

  A += (long)z * sAb + k0;
  B += (long)z * sBb + k0;

  __shared__ alignas(16) __hip_bfloat16 As[2][256 * 64];
  __shared__ alignas(16) __hip_bfloat16 Bs[2][256 * 64];

  v4f acc[8][4] = {};

  // ---- staging geometry: quarter-tile = 64 rows x 64 K = 1 dwordx4/thread.
  // thread covers chunk q = w*64 + l: local row r = q>>3, slot = q&7; that
  // slot must hold global chunk (q&7) ^ (r&7) = (l&7) ^ ((l>>3)&7).
  const int srow = w * 8 + (l >> 3);
  const int scol = (((l & 7) ^ ((l >> 3) & 7)) << 3);
  const __hip_bfloat16* gA = A + (long)(mb + srow) * lda + scol;
  const __hip_bfloat16* gB = B + (long)(nb + srow) * ldb + scol;
  const long qA = 64L * lda, qB = 64L * ldb;
  const int ldst = w * 512;                    // elems: chunk w*64 within quarter

#define STA(QI, T, BUF) __builtin_amdgcn_global_load_lds(                      \
    GBL_AS(gA + (QI) * qA + (T) * 64), LDS_AS(&As[BUF][(QI) * 4096 + ldst]),   \
    16, 0, 0)
#define STB(QI, T, BUF) __builtin_amdgcn_global_load_lds(                      \
    GBL_AS(gB + (QI) * qB + (T) * 64), LDS_AS(&Bs[BUF][(QI) * 4096 + ldst]),   \
    16, 0, 0)
#define SIX(T, BUF) do { STB(0,T,BUF); STB(1,T,BUF); STB(2,T,BUF);             \
                         STB(3,T,BUF); STA(0,T,BUF); STA(2,T,BUF); } while (0)
#define TWO(T, BUF) do { STA(1,T,BUF); STA(3,T,BUF); } while (0)

  // ---- read geometry: A-frag i: row = wr*128 + i*16 + (l&15); chunk =
  // h*4 + (l>>4); (row&7) == (l&7). addr = row*64 + ((chunk ^ (l&7)) << 3).
  const int ldsA0 = (wr * 128 + (l & 15)) * 64;
  const int ldsB0 = (wc * 64 + (l & 15)) * 64;
  const int csw0 = (((l >> 4) ^ (l & 7)) << 3);
  const int csw1 = csw0 ^ 32;                  // chunk | 4 for k-half 1

  // ---- prologue: emulate steady state (six(0), two(0), six(1)) ----
  SIX(0, 0);
  TWO(0, 0);
  if (NT > 1) { SIX(1, 1); WAIT_VM6(); } else { WAIT_VM0(); }
  BAR();

  for (int t = 0; t < NT; ++t) {
    const int b = t & 1;
    const __hip_bfloat16* Ab = As[b];
    const __hip_bfloat16* Bb = Bs[b];
    v8bf a0[4], a1[4], b0[4], b1[4];
    // ---------- P1 ----------
    if (t + 1 < NT) TWO(t + 1, (t + 1) & 1);
#pragma unroll
    for (int i = 0; i < 4; ++i) a0[i] = *(const v8bf*)(Ab + ldsA0 + i * 1024 + csw0);
#pragma unroll
    for (int j = 0; j < 4; ++j) b0[j] = *(const v8bf*)(Bb + ldsB0 + j * 1024 + csw0);
    BAR();
    __builtin_amdgcn_s_setprio(1);
#pragma unroll
    for (int i = 0; i < 4; ++i)
#pragma unroll
      for (int j = 0; j < 4; ++j)
        acc[i][j] = __builtin_amdgcn_mfma_f32_16x16x32_bf16(a0[i], b0[j], acc[i][j], 0, 0, 0);
    __builtin_amdgcn_s_setprio(0);
    BAR();
    // ---------- P2 ----------
#pragma unroll
    for (int i = 0; i < 4; ++i) a1[i] = *(const v8bf*)(Ab + ldsA0 + (i + 4) * 1024 + csw0);
    BAR();
    __builtin_amdgcn_s_setprio(1);
#pragma unroll
    for (int i = 0; i < 4; ++i)
#pragma unroll
      for (int j = 0; j < 4; ++j)
        acc[i + 4][j] = __builtin_amdgcn_mfma_f32_16x16x32_bf16(a1[i], b0[j], acc[i + 4][j], 0, 0, 0);
    __builtin_amdgcn_s_setprio(0);
    BAR();
    // ---------- P3 ----------
#pragma unroll
    for (int i = 0; i < 4; ++i) a0[i] = *(const v8bf*)(Ab + ldsA0 + i * 1024 + csw1);
#pragma unroll
    for (int j = 0; j < 4; ++j) b1[j] = *(const v8bf*)(Bb + ldsB0 + j * 1024 + csw1);
    BAR();
    __builtin_amdgcn_s_setprio(1);
#pragma unroll
    for (int i = 0; i < 4; ++i)
#pragma unroll
      for (int j = 0; j < 4; ++j)
        acc[i][j] = __builtin_amdgcn_mfma_f32_16x16x32_bf16(a0[i], b1[j], acc[i][j], 0, 0, 0);
    __builtin_amdgcn_s_setprio(0);
    BAR();
    // ---------- P4 ----------
    if (t + 2 < NT) SIX(t + 2, b);
#pragma unroll
    for (int i = 0; i < 4; ++i) a1[i] = *(const v8bf*)(Ab + ldsA0 + (i + 4) * 1024 + csw1);
    if (t + 2 < NT) WAIT_VM6(); else WAIT_VM0();
    BAR();
    __builtin_amdgcn_s_setprio(1);
#pragma unroll
    for (int i = 0; i < 4; ++i)
#pragma unroll
      for (int j = 0; j < 4; ++j)
        acc[i + 4][j] = __builtin_amdgcn_mfma_f32_16x16x32_bf16(a1[i], b1[j], acc[i + 4][j], 0, 0, 0);
    __builtin_amdgcn_s_setprio(0);
    BAR();
  }
#undef SIX
#undef TWO
#undef STA
#undef STB

  // ---- epilogue: C/D layout col=lane&15, row=(lane>>4)*4+reg [m89-verified]
  const int col0 = nb + wc * 64 + (l & 15);
  const int row0 = mb + wr * 128 + ((l >> 4) << 2);
  if constexpr (MODE == 0) {
    if (z < 2) {
      __hip_bfloat16* C = (__hip_bfloat16*)Cv + (long)z * sCb;
#pragma unroll
      for (int i = 0; i < 8; ++i)
#pragma unroll
        for (int r = 0; r < 4; ++r) {
          const long ro = (long)(row0 + i * 16 + r) * ldc;
#pragma unroll
          for (int j = 0; j < 4; ++j)
            C[ro + col0 + j * 16] = __float2bfloat16(acc[i][j][r] * scale);
        }
    } else {
      // V projection: write transposed into vT[b][col][seq], 8B packed stores
      const long bb = (long)(row0 >> 11) * 2097152;
      const int seq0 = row0 & 2047;
#pragma unroll
      for (int i = 0; i < 8; ++i)
#pragma unroll
        for (int j = 0; j < 4; ++j) {
          union { __hip_bfloat16 h[4]; uint2 u; } pk;
#pragma unroll
          for (int r = 0; r < 4; ++r) pk.h[r] = __float2bfloat16(acc[i][j][r]);
          *(uint2*)(vTp + bb + (long)(col0 + j * 16) * 2048 + seq0 + i * 16) = pk.u;
        }
    }
  } else if constexpr (MODE == 1) {
    __hip_bfloat16* C = (__hip_bfloat16*)Cv + (long)z * sCb;
    float* srow = sums + z * 2048;
#pragma unroll
    for (int i = 0; i < 8; ++i)
#pragma unroll
      for (int r = 0; r < 4; ++r) {
        const int m = row0 + i * 16 + r;
        const long ro = (long)m * ldc;
        float sp = 0.f;
#pragma unroll
        for (int j = 0; j < 4; ++j) {
          const int n = col0 + j * 16;
          float p = (n <= m) ? __expf(acc[i][j][r] * scale) : 0.0f;
          sp += p;
          C[ro + n] = __float2bfloat16(p);
        }
        sp += __shfl_xor(sp, 1);
        sp += __shfl_xor(sp, 2);
        sp += __shfl_xor(sp, 4);
        sp += __shfl_xor(sp, 8);
        if ((l & 15) == 0) atomicAdd(&srow[m], sp);
      }
  } else {
    float* C = (float*)Cv + (long)z * sCb;
    const float* srow = sums + z * 2048;
#pragma unroll
    for (int i = 0; i < 8; ++i)
#pragma unroll
      for (int r = 0; r < 4; ++r) {
        const int m = row0 + i * 16 + r;
        const float sc = 1.0f / srow[m];
        const long ro = (long)m * ldc;
#pragma unroll
        for (int j = 0; j < 4; ++j) {
          const float v = acc[i][j][r] * sc;
          if (atom) atomicAdd(&C[ro + col0 + j * 16], v);
          else C[ro + col0 + j * 16] = v;
        }
      }
  }
}

__global__ __launch_bounds__(512, 2)
void proj8(const __hip_bfloat16* __restrict__ A, long sAb, int lda,
           const __hip_bfloat16* __restrict__ B, long sBb, int ldb,
           void* __restrict__ Cv, long sCb, int ldc,
           float scale, float* __restrict__ sums,
           __hip_bfloat16* __restrict__ vTp) {
  gemm8_body<0>(A, sAb, lda, B, sBb, ldb, Cv, sCb, ldc, scale, sums, vTp);
}

__global__ __launch_bounds__(512, 2)
void score8(const __hip_bfloat16* __restrict__ A, long sAb, int lda,
            const __hip_bfloat16* __restrict__ B, long sBb, int ldb,
            void* __restrict__ Cv, long sCb, int ldc,
            float scale, float* __restrict__ sums,
            __hip_bfloat16* __restrict__ vTp) {
  gemm8_body<1>(A, sAb, lda, B, sBb, ldb, Cv, sCb, ldc, scale, sums, vTp);
}

__global__ __launch_bounds__(512, 2)
void pv8(const __hip_bfloat16* __restrict__ A, long sAb, int lda,
         const __hip_bfloat16* __restrict__ B, long sBb, int ldb,
         void* __restrict__ Cv, long sCb, int ldc,
         float scale, float* __restrict__ sums,
         __hip_bfloat16* __restrict__ vTp) {
  gemm8_body<2>(A, sAb, lda, B, sBb, ldb, Cv, sCb, ldc, scale, sums, vTp);
}

// ---------------- launch ----------------
extern "C" void kernel_launch(void* const* d_in, const int* in_sizes, int n_in,
                              void* d_out, int out_size, void* d_ws, size_t ws_size,
                              hipStream_t stream) {
  const float* x  = (const float*)d_in[0];
  const float* Wq = (const float*)d_in[1];
  const float* Wk = (const float*)d_in[2];
  const float* Wv = (const float*)d_in[3];
  float* out = (float*)d_out;
  char* ws = (char*)d_ws;

  // ws layout (bytes):
  //   qkv bf16 [3][8192][1024]   @ 0          (48 MB; v-slice unused)
  //   vT  bf16 [4][1024][2048]   @ 50331648   (16 MB)
  //   xb  bf16 [8192][1024]      @ 67108864   (16 MB, dead after proj)
  //   Wb  bf16 [3][1024][1024]   @ 83886080   ( 6 MB, dead after proj)
  //   P   bf16 [4][2048][2048]   @ 67108864   (32 MB, overlaps dead xb/Wb)
  //   sums fp32 [8192]           @ 100663296  (32 KB)
  __hip_bfloat16* qkv = (__hip_bfloat16*)ws;
  __hip_bfloat16* vT  = (__hip_bfloat16*)(ws + 50331648);
  __hip_bfloat16* xb  = (__hip_bfloat16*)(ws + 67108864);
  __hip_bfloat16* Wb  = (__hip_bfloat16*)(ws + 83886080);
  __hip_bfloat16* P   = (__hip_bfloat16*)(ws + 67108864);
  float* sums         = (float*)(ws + 100663296);

  hipMemsetAsync(sums, 0, 8192 * sizeof(float), stream);
  hipMemsetAsync(out, 0, 33554432, stream);   // pv split-K accumulates into out

  cast_f32_bf16<<<8192, 256, 0, stream>>>(x, xb, 8388608);
  cast_w3<<<3072, 256, 0, stream>>>(Wq, Wk, Wv, Wb);

  // qkv projections; z==2 (V) written transposed into vT by the epilogue
  proj8<<<dim3(384, 1, 1), 512, 0, stream>>>(
      xb, 0L, 1024, Wb, 1048576L, 1024, qkv, 8388608L, 1024,
      1.0f, nullptr, vT);

  // P = exp((q@k^T)/32) causal, bf16, fused row-sums (triangular grid 36*4)
  score8<<<dim3(144, 1, 1), 512, 0, stream>>>(
      qkv, 2097152L, 1024, qkv + 8388608, 2097152L, 1024,
      P, 4194304L, 2048, 0.03125f, sums, nullptr);

  // out = (P @ vT^T) / rowsum; split-K (segs <= 1024) + fp32 atomics
  pv8<<<dim3(192, 1, 1), 512, 0, stream>>>(
      P, 4194304L, 2048, vT, 2097152L, 2048,
      out, 2097152L, 1024, 1.0f, sums, nullptr);
}

// Round 3
// 267.109 us; speedup vs baseline: 1.1346x; 1.1346x over previous
//
#include <hip/hip_runtime.h>
#include <hip/hip_bf16.h>

typedef __bf16 v8bf __attribute__((ext_vector_type(8)));
typedef float v4f __attribute__((ext_vector_type(4)));

#define GBL_AS(p) ((const __attribute__((address_space(1))) unsigned int*)(p))
#define LDS_AS(p) ((__attribute__((address_space(3))) unsigned int*)(p))

// s_waitcnt immediates: lgkmcnt=15 (no wait) bits[11:8], expcnt=7 bits[6:4],
// vmcnt low bits[3:0].
#define WAIT_VM3() __builtin_amdgcn_s_waitcnt(0x0F73)  // vmcnt(3)
#define WAIT_VM4() __builtin_amdgcn_s_waitcnt(0x0F74)  // vmcnt(4)
#define WAIT_VM0() __builtin_amdgcn_s_waitcnt(0x0F70)  // vmcnt(0)

// ---------------- fp32 -> bf16 cast (x) ----------------
__global__ void cast_f32_bf16(const float* __restrict__ src,
                              __hip_bfloat16* __restrict__ dst, int n) {
  int i = (blockIdx.x * 256 + threadIdx.x) * 4;
  if (i >= n) return;
  float4 f = *(const float4*)(src + i);
  union { __hip_bfloat16 h[4]; uint2 u; } pk;
  pk.h[0] = __float2bfloat16(f.x);
  pk.h[1] = __float2bfloat16(f.y);
  pk.h[2] = __float2bfloat16(f.z);
  pk.h[3] = __float2bfloat16(f.w);
  *(uint2*)(dst + i) = pk.u;
}

// ---------------- fp32 -> bf16 cast, 3 weight tensors ----------------
__global__ void cast_w3(const float* __restrict__ a, const float* __restrict__ b,
                        const float* __restrict__ c, __hip_bfloat16* __restrict__ dst) {
  int seg = blockIdx.x >> 10;
  const float* src = seg == 0 ? a : (seg == 1 ? b : c);
  int i = ((blockIdx.x & 1023) * 256 + threadIdx.x) * 4;
  float4 f = *(const float4*)(src + i);
  union { __hip_bfloat16 h[4]; uint2 u; } pk;
  pk.h[0] = __float2bfloat16(f.x);
  pk.h[1] = __float2bfloat16(f.y);
  pk.h[2] = __float2bfloat16(f.z);
  pk.h[3] = __float2bfloat16(f.w);
  *(uint2*)(dst + seg * 1048576 + i) = pk.u;
}

// ---------------- projection GEMM: 256x128 tile, 4 waves of 128x64 ----------------
// Round-1 proven kernel, unchanged (68.3 us, MfmaUtil 30%).
// LDS XOR-swizzle: 16B chunk (row r, col-chunk c in 0..3) at slot c ^ ((r>>1)&3);
// realized via permuted per-lane GLOBAL source (DMA dest stays linear), same XOR
// folded into the read base (invariant under +16 rows).
// Per K-step: 6 global_load_lds (A 16KB + B 8KB), triple buffer, vmcnt(6).
__global__ __launch_bounds__(256, 2)
void gemm_proj(const __hip_bfloat16* __restrict__ A, int lda,
               const __hip_bfloat16* __restrict__ B, long sBb, int ldb,
               __hip_bfloat16* __restrict__ C, long sCb, int ldc,
               float scale, __hip_bfloat16* __restrict__ vTp) {
  const int tid = threadIdx.x;
  const int l = tid & 63, w = tid >> 6;
  const int z  = blockIdx.x >> 3;
  const int nb = (blockIdx.x & 7) << 7;   // N-tile: 128 wide
  const int mb = blockIdx.y << 8;         // M-tile: 256 tall

  B += (long)z * sBb;

  __shared__ alignas(16) __hip_bfloat16 As[3][256 * 32];   // 16KB per buf
  __shared__ alignas(16) __hip_bfloat16 Bs[3][128 * 32];   // 8KB per buf

  v4f acc[8][4] = {};
  const int wm = (w >> 1) << 7;   // 0 or 128
  const int wn = (w & 1) << 6;    // 0 or 64

  const int qa0 = 0 * 256 + w * 64 + l, ra0 = qa0 >> 2;
  const int qa1 = 1 * 256 + w * 64 + l, ra1 = qa1 >> 2;
  const int qa2 = 2 * 256 + w * 64 + l, ra2 = qa2 >> 2;
  const int qa3 = 3 * 256 + w * 64 + l, ra3 = qa3 >> 2;
  const __hip_bfloat16* sA0 = A + (long)(mb + ra0) * lda + (((qa0 & 3) ^ ((ra0 >> 1) & 3)) << 3);
  const __hip_bfloat16* sA1 = A + (long)(mb + ra1) * lda + (((qa1 & 3) ^ ((ra1 >> 1) & 3)) << 3);
  const __hip_bfloat16* sA2 = A + (long)(mb + ra2) * lda + (((qa2 & 3) ^ ((ra2 >> 1) & 3)) << 3);
  const __hip_bfloat16* sA3 = A + (long)(mb + ra3) * lda + (((qa3 & 3) ^ ((ra3 >> 1) & 3)) << 3);
  const int qb0 = 0 * 256 + w * 64 + l, rb0 = qb0 >> 2;
  const int qb1 = 1 * 256 + w * 64 + l, rb1 = qb1 >> 2;
  const __hip_bfloat16* sB0 = B + (long)(nb + rb0) * ldb + (((qb0 & 3) ^ ((rb0 >> 1) & 3)) << 3);
  const __hip_bfloat16* sB1 = B + (long)(nb + rb1) * ldb + (((qb1 & 3) ^ ((rb1 >> 1) & 3)) << 3);

  const int arow = wm + (l & 15);
  const int ldsA = arow * 32 + ((((l >> 4) ^ ((arow >> 1) & 3))) << 3);
  const int brow = wn + (l & 15);
  const int ldsB = brow * 32 + ((((l >> 4) ^ ((brow >> 1) & 3))) << 3);

#define STAGE_P(K0, BUF) do {                                                   \
    __builtin_amdgcn_global_load_lds(GBL_AS(sA0 + (K0)),                        \
        LDS_AS(&As[BUF][0 * 2048 + w * 512]), 16, 0, 0);                        \
    __builtin_amdgcn_global_load_lds(GBL_AS(sA1 + (K0)),                        \
        LDS_AS(&As[BUF][1 * 2048 + w * 512]), 16, 0, 0);                        \
    __builtin_amdgcn_global_load_lds(GBL_AS(sA2 + (K0)),                        \
        LDS_AS(&As[BUF][2 * 2048 + w * 512]), 16, 0, 0);                        \
    __builtin_amdgcn_global_load_lds(GBL_AS(sA3 + (K0)),                        \
        LDS_AS(&As[BUF][3 * 2048 + w * 512]), 16, 0, 0);                        \
    __builtin_amdgcn_global_load_lds(GBL_AS(sB0 + (K0)),                        \
        LDS_AS(&Bs[BUF][0 * 2048 + w * 512]), 16, 0, 0);                        \
    __builtin_amdgcn_global_load_lds(GBL_AS(sB1 + (K0)),                        \
        LDS_AS(&Bs[BUF][1 * 2048 + w * 512]), 16, 0, 0);                        \
  } while (0)

#define COMPUTE_P(BI) do {                                                      \
    v8bf af[8], bfr[4];                                                         \
    _Pragma("unroll")                                                           \
    for (int i = 0; i < 8; ++i)                                                 \
      af[i]  = *(const v8bf*)(&As[BI][ldsA + i * 512]);                         \
    _Pragma("unroll")                                                           \
    for (int j = 0; j < 4; ++j)                                                 \
      bfr[j] = *(const v8bf*)(&Bs[BI][ldsB + j * 512]);                         \
    _Pragma("unroll")                                                           \
    for (int i = 0; i < 8; ++i)                                                 \
      _Pragma("unroll")                                                         \
      for (int j = 0; j < 4; ++j)                                               \
        acc[i][j] = __builtin_amdgcn_mfma_f32_16x16x32_bf16(af[i], bfr[j],      \
                                                            acc[i][j], 0, 0, 0);\
  } while (0)

#define WAIT_VM6_() __builtin_amdgcn_s_waitcnt(0x0F76)
#define KITER_P(IT) do {                                                        \
    if constexpr ((IT) < 31) WAIT_VM6_(); else WAIT_VM0();                      \
    __builtin_amdgcn_s_barrier();                                               \
    if constexpr ((IT) < 30) STAGE_P((IT) * 32 + 64, ((IT) + 2) % 3);           \
    COMPUTE_P((IT) % 3);                                                        \
  } while (0)

  STAGE_P(0, 0);
  STAGE_P(32, 1);
  KITER_P(0);  KITER_P(1);  KITER_P(2);  KITER_P(3);  KITER_P(4);  KITER_P(5);
  KITER_P(6);  KITER_P(7);  KITER_P(8);  KITER_P(9);  KITER_P(10); KITER_P(11);
  KITER_P(12); KITER_P(13); KITER_P(14); KITER_P(15); KITER_P(16); KITER_P(17);
  KITER_P(18); KITER_P(19); KITER_P(20); KITER_P(21); KITER_P(22); KITER_P(23);
  KITER_P(24); KITER_P(25); KITER_P(26); KITER_P(27); KITER_P(28); KITER_P(29);
  KITER_P(30); KITER_P(31);
#undef KITER_P
#undef COMPUTE_P
#undef STAGE_P

  // epilogue: C/D layout col=lane&15, row=(lane>>4)*4+reg [m89-verified]
  const int col0 = nb + wn + (l & 15);
  const int row0 = mb + wm + ((l >> 4) << 2);
  if (z < 2) {
    __hip_bfloat16* Cz = C + (long)z * sCb;
#pragma unroll
    for (int i = 0; i < 8; ++i)
#pragma unroll
      for (int r = 0; r < 4; ++r) {
        long ro = (long)(row0 + i * 16 + r) * ldc;
#pragma unroll
        for (int j = 0; j < 4; ++j)
          Cz[ro + col0 + j * 16] = __float2bfloat16(acc[i][j][r] * scale);
      }
  } else {
    // V projection: write transposed into vT[b][col][seq], 8B packed stores
    const long b = row0 >> 11;
    const int seq0 = row0 & 2047;
#pragma unroll
    for (int i = 0; i < 8; ++i)
#pragma unroll
      for (int j = 0; j < 4; ++j) {
        union { __hip_bfloat16 h[4]; uint2 u; } pk;
#pragma unroll
        for (int r = 0; r < 4; ++r) pk.h[r] = __float2bfloat16(acc[i][j][r]);
        *(uint2*)(vTp + b * 2097152 + (long)(col0 + j * 16) * 2048 +
                  (seq0 + i * 16)) = pk.u;
      }
  }
}

// ---------------- scores: 64x128 tile, 4 waves of 64x32 ----------------
// NEW geometry, SAME proven staging/swizzle/pipeline algebra as r1.
// Rationale: r1 score ran 271 TF vs proj 757 TF with an identical inner loop;
// the only structural difference was grid fill (544 blocks = 2.1/CU). 64-row
// tiles give 1088 blocks at 4/CU (LDS 36KB, bounds(256,4)) -> 2x resident waves.
// Per K-step: 3 global_load_lds (A 4KB + B 8KB), triple buffer, vmcnt(3).
// P = exp(s*scale) causal, bf16 out, fused row-sum atomics.
__global__ __launch_bounds__(256, 4)
void gemm_score64(const __hip_bfloat16* __restrict__ A, long sAb,
                  const __hip_bfloat16* __restrict__ B, long sBb,
                  __hip_bfloat16* __restrict__ C, long sCb,
                  float scale, float* __restrict__ sums) {
  const int tid = threadIdx.x;
  const int l = tid & 63, w = tid >> 6;
  const int id = blockIdx.x;            // 1088 = 4z * 272
  const int z = id / 272;
  const int t = id - z * 272;
  // causal 64x128 tiles: mm in 0..31, nn <= mm>>1. pairs p = mm>>1:
  // base(p) = p*(p+1); rem in [0, 2p+2): mm = 2p + (rem>p), nn = rem - (rem>p)*(p+1)
  int p = (int)((__builtin_sqrtf(4.0f * t + 1.0f) - 1.0f) * 0.5f);
  while ((p + 1) * (p + 2) <= t) ++p;
  while (p * (p + 1) > t) --p;
  const int rem = t - p * (p + 1);
  const int mm = 2 * p + (rem > p);
  const int nn = (rem > p) ? rem - (p + 1) : rem;
  const int mb = mm << 6, nb = nn << 7;

  const __hip_bfloat16* Az = A + (long)z * sAb;   // q
  const __hip_bfloat16* Bz = B + (long)z * sBb;   // k

  __shared__ alignas(16) __hip_bfloat16 As[3][64 * 32];    // 4KB per buf
  __shared__ alignas(16) __hip_bfloat16 Bs[3][128 * 32];   // 8KB per buf

  v4f acc[4][2] = {};
  const int wn = w << 5;                // wave covers 32 cols

  // A staging: 256 chunks, 1/thread. chunk q=tid -> row q>>2, col-chunk
  // (q&3)^((row>>1)&3)  [swizzle inverse, same algebra as r1]
  const int ras = tid >> 2;
  const int cas = ((tid & 3) ^ ((ras >> 1) & 3)) << 3;
  const __hip_bfloat16* Arow = Az + (long)(mb + ras) * 1024 + cas;
  // B staging: 512 chunks, 2/thread (q0=tid, q1=256+tid)
  const int r0s = tid >> 2;
  const int c0s = ((tid & 3) ^ ((r0s >> 1) & 3)) << 3;
  const int q1 = 256 + tid, r1s = q1 >> 2;
  const int c1s = ((q1 & 3) ^ ((r1s >> 1) & 3)) << 3;
  const __hip_bfloat16* Brow0 = Bz + (long)(nb + r0s) * 1024 + c0s;
  const __hip_bfloat16* Brow1 = Bz + (long)(nb + r1s) * 1024 + c1s;

  // swizzled read bases
  const int arow = l & 15;              // wm = 0 (all waves share rows)
  const int ldsA = arow * 32 + ((((l >> 4) ^ ((arow >> 1) & 3))) << 3);
  const int brow = wn + (l & 15);
  const int ldsB = brow * 32 + ((((l >> 4) ^ ((brow >> 1) & 3))) << 3);

#define STAGE_S(K0, BUF) do {                                                   \
    __builtin_amdgcn_global_load_lds(GBL_AS(Arow + (K0)),                       \
        LDS_AS(&As[BUF][tid * 8]), 16, 0, 0);                                   \
    __builtin_amdgcn_global_load_lds(GBL_AS(Brow0 + (K0)),                      \
        LDS_AS(&Bs[BUF][tid * 8]), 16, 0, 0);                                   \
    __builtin_amdgcn_global_load_lds(GBL_AS(Brow1 + (K0)),                      \
        LDS_AS(&Bs[BUF][2048 + tid * 8]), 16, 0, 0);                            \
  } while (0)

#define COMPUTE_S(BI) do {                                                      \
    v8bf af[4], bfr[2];                                                         \
    _Pragma("unroll")                                                           \
    for (int i = 0; i < 4; ++i)                                                 \
      af[i]  = *(const v8bf*)(&As[BI][ldsA + i * 512]);                         \
    _Pragma("unroll")                                                           \
    for (int j = 0; j < 2; ++j)                                                 \
      bfr[j] = *(const v8bf*)(&Bs[BI][ldsB + j * 512]);                         \
    _Pragma("unroll")                                                           \
    for (int i = 0; i < 4; ++i)                                                 \
      _Pragma("unroll")                                                         \
      for (int j = 0; j < 2; ++j)                                               \
        acc[i][j] = __builtin_amdgcn_mfma_f32_16x16x32_bf16(af[i], bfr[j],      \
                                                            acc[i][j], 0, 0, 0);\
  } while (0)

#define KITER_S(IT) do {                                                        \
    if constexpr ((IT) < 31) WAIT_VM3(); else WAIT_VM0();                       \
    __builtin_amdgcn_s_barrier();                                               \
    if constexpr ((IT) < 30) STAGE_S((IT) * 32 + 64, ((IT) + 2) % 3);           \
    COMPUTE_S((IT) % 3);                                                        \
  } while (0)

  STAGE_S(0, 0);
  STAGE_S(32, 1);
  KITER_S(0);  KITER_S(1);  KITER_S(2);  KITER_S(3);  KITER_S(4);  KITER_S(5);
  KITER_S(6);  KITER_S(7);  KITER_S(8);  KITER_S(9);  KITER_S(10); KITER_S(11);
  KITER_S(12); KITER_S(13); KITER_S(14); KITER_S(15); KITER_S(16); KITER_S(17);
  KITER_S(18); KITER_S(19); KITER_S(20); KITER_S(21); KITER_S(22); KITER_S(23);
  KITER_S(24); KITER_S(25); KITER_S(26); KITER_S(27); KITER_S(28); KITER_S(29);
  KITER_S(30); KITER_S(31);
#undef KITER_S
#undef COMPUTE_S
#undef STAGE_S

  // epilogue: exp + causal mask + bf16 store + fused row-sum atomics
  __hip_bfloat16* Cz = C + (long)z * sCb;
  float* srow = sums + z * 2048;
  const int col0 = nb + wn + (l & 15);
  const int row0 = mb + ((l >> 4) << 2);
#pragma unroll
  for (int i = 0; i < 4; ++i)
#pragma unroll
    for (int r = 0; r < 4; ++r) {
      const int m = row0 + i * 16 + r;
      const long ro = (long)m * 2048;
      float sp = 0.f;
#pragma unroll
      for (int j = 0; j < 2; ++j) {
        const int n = col0 + j * 16;
        float pv = (n <= m) ? __expf(acc[i][j][r] * scale) : 0.0f;
        sp += pv;
        Cz[ro + n] = __float2bfloat16(pv);
      }
      sp += __shfl_xor(sp, 1);
      sp += __shfl_xor(sp, 2);
      sp += __shfl_xor(sp, 4);
      sp += __shfl_xor(sp, 8);
      if ((l & 15) == 0) atomicAdd(&srow[m], sp);
    }
}

// ---------------- PV: 128x128 tile, split-K, 4 waves of 64x64 ----------------
// r1 MODE2 template with split-K grid (r2-proven decode/atomics): rows m>=8
// (K>1024) split into two segments of <=1024; 768 blocks = exactly 3/CU.
// Upper-half output pre-zeroed by host-side memset; split segs atomicAdd fp32.
__global__ __launch_bounds__(256, 3)
void gemm_pv(const __hip_bfloat16* __restrict__ A, long sAb, int lda,
             const __hip_bfloat16* __restrict__ B, long sBb, int ldb,
             float* __restrict__ C, long sCb, int ldc,
             const float* __restrict__ sums) {
  const int tid = threadIdx.x;
  const int l = tid & 63, w = tid >> 6;
  const int id = blockIdx.x;            // 768 = 4z * 8nn * 24s
  const int z = id / 192;
  const int rem = id - z * 192;
  const int nn = rem / 24, s = rem - nn * 24;
  int m, k0s, klen;
  bool atom;
  if (s < 8) {
    m = s; k0s = 0; klen = (m + 1) << 7; atom = false;
  } else {
    const int u = s - 8;
    m = 8 + (u >> 1);
    const int h = ((m + 1) >> 1) << 7;  // split point (multiple of 128)
    if (u & 1) { k0s = h; klen = ((m + 1) << 7) - h; }
    else       { k0s = 0; klen = h; }
    atom = true;
  }
  const int mb = m << 7, nb = nn << 7;

  A += (long)z * sAb + k0s;   // P  (lda = 2048)
  B += (long)z * sBb + k0s;   // vT (ldb = 2048)

  __shared__ alignas(16) __hip_bfloat16 As[3][128 * 32];
  __shared__ alignas(16) __hip_bfloat16 Bs[3][128 * 32];

  v4f acc[4][4] = {};
  const int wm = (w >> 1) * 64, wn = (w & 1) * 64;

  const int cb0 = w * 64;
  const int q0 = cb0 + l, r0s = q0 >> 2;
  const int c0s = ((q0 & 3) ^ ((r0s >> 1) & 3)) << 3;
  const int cb1 = 256 + w * 64;
  const int q1 = cb1 + l, r1s = q1 >> 2;
  const int c1s = ((q1 & 3) ^ ((r1s >> 1) & 3)) << 3;

  const __hip_bfloat16* Arow0 = A + (long)(mb + r0s) * lda + c0s;
  const __hip_bfloat16* Arow1 = A + (long)(mb + r1s) * lda + c1s;
  const __hip_bfloat16* Brow0 = B + (long)(nb + r0s) * ldb + c0s;
  const __hip_bfloat16* Brow1 = B + (long)(nb + r1s) * ldb + c1s;

  const int arow = wm + (l & 15);
  const int ldsA = arow * 32 + ((((l >> 4) ^ ((arow >> 1) & 3))) << 3);
  const int brow = wn + (l & 15);
  const int ldsB = brow * 32 + ((((l >> 4) ^ ((brow >> 1) & 3))) << 3);

  auto stage = [&](int k0, int buf) {
    __builtin_amdgcn_global_load_lds(GBL_AS(Arow0 + k0),
        LDS_AS(&As[buf][cb0 * 8]), 16, 0, 0);
    __builtin_amdgcn_global_load_lds(GBL_AS(Brow0 + k0),
        LDS_AS(&Bs[buf][cb0 * 8]), 16, 0, 0);
    __builtin_amdgcn_global_load_lds(GBL_AS(Arow1 + k0),
        LDS_AS(&As[buf][cb1 * 8]), 16, 0, 0);
    __builtin_amdgcn_global_load_lds(GBL_AS(Brow1 + k0),
        LDS_AS(&Bs[buf][cb1 * 8]), 16, 0, 0);
  };
  stage(0, 0);
  if (32 < klen) stage(32, 1);
  int bi = 0;
  for (int k0 = 0; k0 < klen; k0 += 32) {
    if (k0 + 32 < klen) WAIT_VM4(); else WAIT_VM0();
    __builtin_amdgcn_s_barrier();
    if (k0 + 64 < klen) stage(k0 + 64, bi == 0 ? 2 : bi - 1);
    v8bf af[4], bfr[4];
#pragma unroll
    for (int i = 0; i < 4; ++i) {
      af[i]  = *(const v8bf*)(&As[bi][ldsA + i * 512]);
      bfr[i] = *(const v8bf*)(&Bs[bi][ldsB + i * 512]);
    }
#pragma unroll
    for (int i = 0; i < 4; ++i)
#pragma unroll
      for (int j = 0; j < 4; ++j)
        acc[i][j] = __builtin_amdgcn_mfma_f32_16x16x32_bf16(af[i], bfr[j], acc[i][j], 0, 0, 0);
    bi = (bi == 2) ? 0 : bi + 1;
  }

  // epilogue: divide by rowsum; split rows accumulate atomically (pre-zeroed)
  float* Cz = C + (long)z * sCb;
  const float* srow = sums + z * 2048;
  const int col0 = nb + wn + (l & 15);
  const int row0 = mb + wm + ((l >> 4) << 2);
#pragma unroll
  for (int i = 0; i < 4; ++i)
#pragma unroll
    for (int r = 0; r < 4; ++r) {
      const int mr = row0 + i * 16 + r;
      const float sc = 1.0f / srow[mr];
      const long ro = (long)mr * ldc;
#pragma unroll
      for (int j = 0; j < 4; ++j) {
        const float v = acc[i][j][r] * sc;
        if (atom) atomicAdd(&Cz[ro + col0 + j * 16], v);
        else Cz[ro + col0 + j * 16] = v;
      }
    }
}

// ---------------- launch ----------------
extern "C" void kernel_launch(void* const* d_in, const int* in_sizes, int n_in,
                              void* d_out, int out_size, void* d_ws, size_t ws_size,
                              hipStream_t stream) {
  const float* x  = (const float*)d_in[0];
  const float* Wq = (const float*)d_in[1];
  const float* Wk = (const float*)d_in[2];
  const float* Wv = (const float*)d_in[3];
  float* out = (float*)d_out;
  char* ws = (char*)d_ws;

  // ws layout (bytes):
  //   qkv bf16 [3][8192][1024]   @ 0          (48 MB; v-slice unused)
  //   vT  bf16 [4][1024][2048]   @ 50331648   (16 MB)
  //   xb  bf16 [8192][1024]      @ 67108864   (16 MB, dead after proj)
  //   Wb  bf16 [3][1024][1024]   @ 83886080   ( 6 MB, dead after proj)
  //   P   bf16 [4][2048][2048]   @ 67108864   (32 MB, overlaps dead xb/Wb)
  //   sums fp32 [8192]           @ 100663296  (32 KB)
  __hip_bfloat16* qkv = (__hip_bfloat16*)ws;
  __hip_bfloat16* vT  = (__hip_bfloat16*)(ws + 50331648);
  __hip_bfloat16* xb  = (__hip_bfloat16*)(ws + 67108864);
  __hip_bfloat16* Wb  = (__hip_bfloat16*)(ws + 83886080);
  __hip_bfloat16* P   = (__hip_bfloat16*)(ws + 67108864);
  float* sums         = (float*)(ws + 100663296);

  hipMemsetAsync(sums, 0, 8192 * sizeof(float), stream);
  // zero rows 1024..2047 of each z-slice of out (split-K atomic targets)
  for (int z = 0; z < 4; ++z)
    hipMemsetAsync(out + (long)z * 2097152 + 1048576, 0, 4194304, stream);

  cast_f32_bf16<<<8192, 256, 0, stream>>>(x, xb, 8388608);
  cast_w3<<<3072, 256, 0, stream>>>(Wq, Wk, Wv, Wb);

  // qkv projections; z==2 (V) written transposed into vT by the epilogue
  gemm_proj<<<dim3(24, 32, 1), 256, 0, stream>>>(
      xb, 1024, Wb, 1048576L, 1024, qkv, 8388608L, 1024, 1.0f, vT);

  // P = exp((q@k^T)/32) causal, bf16, fused row-sums (64x128 tiles, 1088 blocks)
  gemm_score64<<<dim3(1088, 1, 1), 256, 0, stream>>>(
      qkv, 2097152L, qkv + 8388608, 2097152L,
      P, 4194304L, 0.03125f, sums);

  // out = (P @ vT^T) / rowsum; split-K (segs <= 1024), 768 blocks = 3/CU
  gemm_pv<<<dim3(768, 1, 1), 256, 0, stream>>>(
      P, 4194304L, 2048, vT, 2097152L, 2048,
      out, 2097152L, 1024, sums);
}

// Round 4
// 230.832 us; speedup vs baseline: 1.3129x; 1.1572x over previous
//
#include <hip/hip_runtime.h>
#include <hip/hip_bf16.h>

typedef __bf16 v8bf __attribute__((ext_vector_type(8)));
typedef float v4f __attribute__((ext_vector_type(4)));

#define GBL_AS(p) ((const __attribute__((address_space(1))) unsigned int*)(p))
#define LDS_AS(p) ((__attribute__((address_space(3))) unsigned int*)(p))

// s_waitcnt immediates: lgkmcnt=15 (no wait) bits[11:8], expcnt=7 bits[6:4],
// vmcnt low bits[3:0].
#define WAIT_VM4() __builtin_amdgcn_s_waitcnt(0x0F74)  // vmcnt(4)
#define WAIT_VM6() __builtin_amdgcn_s_waitcnt(0x0F76)  // vmcnt(6)
#define WAIT_VM0() __builtin_amdgcn_s_waitcnt(0x0F70)  // vmcnt(0)

// ---------------- fp32 -> bf16 cast (x) ----------------
__global__ void cast_f32_bf16(const float* __restrict__ src,
                              __hip_bfloat16* __restrict__ dst, int n) {
  int i = (blockIdx.x * 256 + threadIdx.x) * 4;
  if (i >= n) return;
  float4 f = *(const float4*)(src + i);
  union { __hip_bfloat16 h[4]; uint2 u; } pk;
  pk.h[0] = __float2bfloat16(f.x);
  pk.h[1] = __float2bfloat16(f.y);
  pk.h[2] = __float2bfloat16(f.z);
  pk.h[3] = __float2bfloat16(f.w);
  *(uint2*)(dst + i) = pk.u;
}

// ---------------- fp32 -> bf16 cast, 3 weight tensors ----------------
__global__ void cast_w3(const float* __restrict__ a, const float* __restrict__ b,
                        const float* __restrict__ c, __hip_bfloat16* __restrict__ dst) {
  int seg = blockIdx.x >> 10;
  const float* src = seg == 0 ? a : (seg == 1 ? b : c);
  int i = ((blockIdx.x & 1023) * 256 + threadIdx.x) * 4;
  float4 f = *(const float4*)(src + i);
  union { __hip_bfloat16 h[4]; uint2 u; } pk;
  pk.h[0] = __float2bfloat16(f.x);
  pk.h[1] = __float2bfloat16(f.y);
  pk.h[2] = __float2bfloat16(f.z);
  pk.h[3] = __float2bfloat16(f.w);
  *(uint2*)(dst + seg * 1048576 + i) = pk.u;
}

// ---------------- projection GEMM: 256x128 tile, 4 waves of 128x64 ----------------
// Round-1 proven kernel, unchanged (68.3 us, MfmaUtil 30%, FETCH 74 MB).
// Natural dispatch order already gives good Wb L2 reuse -> no XCD remap here.
__global__ __launch_bounds__(256, 2)
void gemm_proj(const __hip_bfloat16* __restrict__ A, int lda,
               const __hip_bfloat16* __restrict__ B, long sBb, int ldb,
               __hip_bfloat16* __restrict__ C, long sCb, int ldc,
               float scale, __hip_bfloat16* __restrict__ vTp) {
  const int tid = threadIdx.x;
  const int l = tid & 63, w = tid >> 6;
  const int z  = blockIdx.x >> 3;
  const int nb = (blockIdx.x & 7) << 7;   // N-tile: 128 wide
  const int mb = blockIdx.y << 8;         // M-tile: 256 tall

  B += (long)z * sBb;

  __shared__ alignas(16) __hip_bfloat16 As[3][256 * 32];   // 16KB per buf
  __shared__ alignas(16) __hip_bfloat16 Bs[3][128 * 32];   // 8KB per buf

  v4f acc[8][4] = {};
  const int wm = (w >> 1) << 7;   // 0 or 128
  const int wn = (w & 1) << 6;    // 0 or 64

  const int qa0 = 0 * 256 + w * 64 + l, ra0 = qa0 >> 2;
  const int qa1 = 1 * 256 + w * 64 + l, ra1 = qa1 >> 2;
  const int qa2 = 2 * 256 + w * 64 + l, ra2 = qa2 >> 2;
  const int qa3 = 3 * 256 + w * 64 + l, ra3 = qa3 >> 2;
  const __hip_bfloat16* sA0 = A + (long)(mb + ra0) * lda + (((qa0 & 3) ^ ((ra0 >> 1) & 3)) << 3);
  const __hip_bfloat16* sA1 = A + (long)(mb + ra1) * lda + (((qa1 & 3) ^ ((ra1 >> 1) & 3)) << 3);
  const __hip_bfloat16* sA2 = A + (long)(mb + ra2) * lda + (((qa2 & 3) ^ ((ra2 >> 1) & 3)) << 3);
  const __hip_bfloat16* sA3 = A + (long)(mb + ra3) * lda + (((qa3 & 3) ^ ((ra3 >> 1) & 3)) << 3);
  const int qb0 = 0 * 256 + w * 64 + l, rb0 = qb0 >> 2;
  const int qb1 = 1 * 256 + w * 64 + l, rb1 = qb1 >> 2;
  const __hip_bfloat16* sB0 = B + (long)(nb + rb0) * ldb + (((qb0 & 3) ^ ((rb0 >> 1) & 3)) << 3);
  const __hip_bfloat16* sB1 = B + (long)(nb + rb1) * ldb + (((qb1 & 3) ^ ((rb1 >> 1) & 3)) << 3);

  const int arow = wm + (l & 15);
  const int ldsA = arow * 32 + ((((l >> 4) ^ ((arow >> 1) & 3))) << 3);
  const int brow = wn + (l & 15);
  const int ldsB = brow * 32 + ((((l >> 4) ^ ((brow >> 1) & 3))) << 3);

#define STAGE_P(K0, BUF) do {                                                   \
    __builtin_amdgcn_global_load_lds(GBL_AS(sA0 + (K0)),                        \
        LDS_AS(&As[BUF][0 * 2048 + w * 512]), 16, 0, 0);                        \
    __builtin_amdgcn_global_load_lds(GBL_AS(sA1 + (K0)),                        \
        LDS_AS(&As[BUF][1 * 2048 + w * 512]), 16, 0, 0);                        \
    __builtin_amdgcn_global_load_lds(GBL_AS(sA2 + (K0)),                        \
        LDS_AS(&As[BUF][2 * 2048 + w * 512]), 16, 0, 0);                        \
    __builtin_amdgcn_global_load_lds(GBL_AS(sA3 + (K0)),                        \
        LDS_AS(&As[BUF][3 * 2048 + w * 512]), 16, 0, 0);                        \
    __builtin_amdgcn_global_load_lds(GBL_AS(sB0 + (K0)),                        \
        LDS_AS(&Bs[BUF][0 * 2048 + w * 512]), 16, 0, 0);                        \
    __builtin_amdgcn_global_load_lds(GBL_AS(sB1 + (K0)),                        \
        LDS_AS(&Bs[BUF][1 * 2048 + w * 512]), 16, 0, 0);                        \
  } while (0)

#define COMPUTE_P(BI) do {                                                      \
    v8bf af[8], bfr[4];                                                         \
    _Pragma("unroll")                                                           \
    for (int i = 0; i < 8; ++i)                                                 \
      af[i]  = *(const v8bf*)(&As[BI][ldsA + i * 512]);                         \
    _Pragma("unroll")                                                           \
    for (int j = 0; j < 4; ++j)                                                 \
      bfr[j] = *(const v8bf*)(&Bs[BI][ldsB + j * 512]);                         \
    _Pragma("unroll")                                                           \
    for (int i = 0; i < 8; ++i)                                                 \
      _Pragma("unroll")                                                         \
      for (int j = 0; j < 4; ++j)                                               \
        acc[i][j] = __builtin_amdgcn_mfma_f32_16x16x32_bf16(af[i], bfr[j],      \
                                                            acc[i][j], 0, 0, 0);\
  } while (0)

#define KITER_P(IT) do {                                                        \
    if constexpr ((IT) < 31) WAIT_VM6(); else WAIT_VM0();                       \
    __builtin_amdgcn_s_barrier();                                               \
    if constexpr ((IT) < 30) STAGE_P((IT) * 32 + 64, ((IT) + 2) % 3);           \
    COMPUTE_P((IT) % 3);                                                        \
  } while (0)

  STAGE_P(0, 0);
  STAGE_P(32, 1);
  KITER_P(0);  KITER_P(1);  KITER_P(2);  KITER_P(3);  KITER_P(4);  KITER_P(5);
  KITER_P(6);  KITER_P(7);  KITER_P(8);  KITER_P(9);  KITER_P(10); KITER_P(11);
  KITER_P(12); KITER_P(13); KITER_P(14); KITER_P(15); KITER_P(16); KITER_P(17);
  KITER_P(18); KITER_P(19); KITER_P(20); KITER_P(21); KITER_P(22); KITER_P(23);
  KITER_P(24); KITER_P(25); KITER_P(26); KITER_P(27); KITER_P(28); KITER_P(29);
  KITER_P(30); KITER_P(31);
#undef KITER_P
#undef COMPUTE_P
#undef STAGE_P

  // epilogue: C/D layout col=lane&15, row=(lane>>4)*4+reg [m89-verified]
  const int col0 = nb + wn + (l & 15);
  const int row0 = mb + wm + ((l >> 4) << 2);
  if (z < 2) {
    __hip_bfloat16* Cz = C + (long)z * sCb;
#pragma unroll
    for (int i = 0; i < 8; ++i)
#pragma unroll
      for (int r = 0; r < 4; ++r) {
        long ro = (long)(row0 + i * 16 + r) * ldc;
#pragma unroll
        for (int j = 0; j < 4; ++j)
          Cz[ro + col0 + j * 16] = __float2bfloat16(acc[i][j][r] * scale);
      }
  } else {
    // V projection: write transposed into vT[b][col][seq], 8B packed stores
    const long b = row0 >> 11;
    const int seq0 = row0 & 2047;
#pragma unroll
    for (int i = 0; i < 8; ++i)
#pragma unroll
      for (int j = 0; j < 4; ++j) {
        union { __hip_bfloat16 h[4]; uint2 u; } pk;
#pragma unroll
        for (int r = 0; r < 4; ++r) pk.h[r] = __float2bfloat16(acc[i][j][r]);
        *(uint2*)(vTp + b * 2097152 + (long)(col0 + j * 16) * 2048 +
                  (seq0 + i * 16)) = pk.u;
      }
  }
}

// ---------------- scores: 128x128 tile (r1 body) + XCD-chunked schedule ----------
// THEORY (r4): score is L2-miss-traffic bound (272 MB streamed; qkv 32MB >> 4MB
// per-XCD L2; round-robin dispatch kills tile reuse). Remap so XCD x = id&7
// processes a CONTIGUOUS triangular range w = x*68 + id>>3 (bijective, 544=8*68).
// t-order is m-major: A q-row-tile stays L2-hot across its row; B k-tiles
// (n=0..m, <=4MB) nest across consecutive rows -> mostly L2-resident.
// Predicted per-XCD traffic ~7MB -> ~56MB total (was 272MB).
__global__ __launch_bounds__(256, 3)
void gemm_score(const __hip_bfloat16* __restrict__ A, long sAb,
                const __hip_bfloat16* __restrict__ B, long sBb,
                __hip_bfloat16* __restrict__ C, long sCb,
                float scale, float* __restrict__ sums) {
  const int tid = threadIdx.x;
  const int l = tid & 63, w = tid >> 6;
  // XCD-chunked decode: 544 blocks = 8 XCDs x 68 work items
  const int id = blockIdx.x;
  const int wk = (id & 7) * 68 + (id >> 3);
  const int z = wk / 136;
  const int t = wk - z * 136;                    // 0..135 triangular, m-major
  int m = (int)((__builtin_sqrtf(8.0f * t + 1.0f) - 1.0f) * 0.5f);
  while ((m + 1) * (m + 2) / 2 <= t) ++m;
  while (m * (m + 1) / 2 > t) --m;
  const int mb = m << 7;
  const int nb = (t - m * (m + 1) / 2) << 7;

  const __hip_bfloat16* Az = A + (long)z * sAb;
  const __hip_bfloat16* Bz = B + (long)z * sBb;

  __shared__ alignas(16) __hip_bfloat16 As[3][128 * 32];
  __shared__ alignas(16) __hip_bfloat16 Bs[3][128 * 32];

  v4f acc[4][4] = {};
  const int wm = (w >> 1) * 64, wn = (w & 1) * 64;

  const int cb0 = w * 64;
  const int q0 = cb0 + l, r0s = q0 >> 2;
  const int c0s = ((q0 & 3) ^ ((r0s >> 1) & 3)) << 3;
  const int cb1 = 256 + w * 64;
  const int q1 = cb1 + l, r1s = q1 >> 2;
  const int c1s = ((q1 & 3) ^ ((r1s >> 1) & 3)) << 3;

  const __hip_bfloat16* Arow0 = Az + (long)(mb + r0s) * 1024 + c0s;
  const __hip_bfloat16* Arow1 = Az + (long)(mb + r1s) * 1024 + c1s;
  const __hip_bfloat16* Brow0 = Bz + (long)(nb + r0s) * 1024 + c0s;
  const __hip_bfloat16* Brow1 = Bz + (long)(nb + r1s) * 1024 + c1s;

  const int arow = wm + (l & 15);
  const int ldsA = arow * 32 + ((((l >> 4) ^ ((arow >> 1) & 3))) << 3);
  const int brow = wn + (l & 15);
  const int ldsB = brow * 32 + ((((l >> 4) ^ ((brow >> 1) & 3))) << 3);

#define STAGE_S(K0, BUF) do {                                                   \
    __builtin_amdgcn_global_load_lds(GBL_AS(Arow0 + (K0)),                      \
        LDS_AS(&As[BUF][cb0 * 8]), 16, 0, 0);                                   \
    __builtin_amdgcn_global_load_lds(GBL_AS(Brow0 + (K0)),                      \
        LDS_AS(&Bs[BUF][cb0 * 8]), 16, 0, 0);                                   \
    __builtin_amdgcn_global_load_lds(GBL_AS(Arow1 + (K0)),                      \
        LDS_AS(&As[BUF][cb1 * 8]), 16, 0, 0);                                   \
    __builtin_amdgcn_global_load_lds(GBL_AS(Brow1 + (K0)),                      \
        LDS_AS(&Bs[BUF][cb1 * 8]), 16, 0, 0);                                   \
  } while (0)

#define COMPUTE_S(BI) do {                                                      \
    v8bf af[4], bfr[4];                                                         \
    _Pragma("unroll")                                                           \
    for (int i = 0; i < 4; ++i) {                                               \
      af[i]  = *(const v8bf*)(&As[BI][ldsA + i * 512]);                         \
      bfr[i] = *(const v8bf*)(&Bs[BI][ldsB + i * 512]);                         \
    }                                                                           \
    _Pragma("unroll")                                                           \
    for (int i = 0; i < 4; ++i)                                                 \
      _Pragma("unroll")                                                         \
      for (int j = 0; j < 4; ++j)                                               \
        acc[i][j] = __builtin_amdgcn_mfma_f32_16x16x32_bf16(af[i], bfr[j],      \
                                                            acc[i][j], 0, 0, 0);\
  } while (0)

#define KITER_S(IT) do {                                                        \
    if constexpr ((IT) < 31) WAIT_VM4(); else WAIT_VM0();                       \
    __builtin_amdgcn_s_barrier();                                               \
    if constexpr ((IT) < 30) STAGE_S((IT) * 32 + 64, ((IT) + 2) % 3);           \
    COMPUTE_S((IT) % 3);                                                        \
  } while (0)

  STAGE_S(0, 0);
  STAGE_S(32, 1);
  KITER_S(0);  KITER_S(1);  KITER_S(2);  KITER_S(3);  KITER_S(4);  KITER_S(5);
  KITER_S(6);  KITER_S(7);  KITER_S(8);  KITER_S(9);  KITER_S(10); KITER_S(11);
  KITER_S(12); KITER_S(13); KITER_S(14); KITER_S(15); KITER_S(16); KITER_S(17);
  KITER_S(18); KITER_S(19); KITER_S(20); KITER_S(21); KITER_S(22); KITER_S(23);
  KITER_S(24); KITER_S(25); KITER_S(26); KITER_S(27); KITER_S(28); KITER_S(29);
  KITER_S(30); KITER_S(31);
#undef KITER_S
#undef COMPUTE_S
#undef STAGE_S

  // epilogue: exp + causal mask + bf16 store + fused row-sum atomics
  __hip_bfloat16* Cz = C + (long)z * sCb;
  float* srow = sums + z * 2048;
  const int col0 = nb + wn + (l & 15);
  const int row0 = mb + wm + ((l >> 4) << 2);
#pragma unroll
  for (int i = 0; i < 4; ++i)
#pragma unroll
    for (int r = 0; r < 4; ++r) {
      const int mm = row0 + i * 16 + r;
      const long ro = (long)mm * 2048;
      float sp = 0.f;
#pragma unroll
      for (int j = 0; j < 4; ++j) {
        const int n = col0 + j * 16;
        float pv = (n <= mm) ? __expf(acc[i][j][r] * scale) : 0.0f;
        sp += pv;
        Cz[ro + n] = __float2bfloat16(pv);
      }
      sp += __shfl_xor(sp, 1);
      sp += __shfl_xor(sp, 2);
      sp += __shfl_xor(sp, 4);
      sp += __shfl_xor(sp, 8);
      if ((l & 15) == 0) atomicAdd(&srow[mm], sp);
    }
}

// ---------------- PV: 128x128 tile (r1 body) + XCD-chunked schedule ----------
// Same traffic theory. 512 blocks = 8 XCDs x 64. XCD x: z = x>>1, output-col
// tiles nb in {(x&1)*4 .. +3} (its 4 vT B-tiles = 2MB stay L2-resident across
// ALL m-visits -> B read once per XCD), m descending (big-K first, tail-safe),
// nb fastest (A P-row-tile hot across its 4 uses). Predicted ~50MB total
// (was ~300MB effective).
__global__ __launch_bounds__(256, 3)
void gemm_pv(const __hip_bfloat16* __restrict__ A, long sAb, int lda,
             const __hip_bfloat16* __restrict__ B, long sBb, int ldb,
             float* __restrict__ C, long sCb, int ldc,
             const float* __restrict__ sums) {
  const int tid = threadIdx.x;
  const int l = tid & 63, w = tid >> 6;
  const int id = blockIdx.x;            // 512 = 8 XCD x 64
  const int x = id & 7, j = id >> 3;
  const int z = x >> 1;
  const int nb = (((x & 1) << 2) | (j & 3)) << 7;   // 8 col-tiles split 4+4
  const int m = 15 - (j >> 2);                      // descending K
  const int mb = m << 7;
  const int kend = (m + 1) << 7;

  A += (long)z * sAb;   // P  (lda = 2048)
  B += (long)z * sBb;   // vT (ldb = 2048)

  __shared__ alignas(16) __hip_bfloat16 As[3][128 * 32];
  __shared__ alignas(16) __hip_bfloat16 Bs[3][128 * 32];

  v4f acc[4][4] = {};
  const int wm = (w >> 1) * 64, wn = (w & 1) * 64;

  const int cb0 = w * 64;
  const int q0 = cb0 + l, r0s = q0 >> 2;
  const int c0s = ((q0 & 3) ^ ((r0s >> 1) & 3)) << 3;
  const int cb1 = 256 + w * 64;
  const int q1 = cb1 + l, r1s = q1 >> 2;
  const int c1s = ((q1 & 3) ^ ((r1s >> 1) & 3)) << 3;

  const __hip_bfloat16* Arow0 = A + (long)(mb + r0s) * lda + c0s;
  const __hip_bfloat16* Arow1 = A + (long)(mb + r1s) * lda + c1s;
  const __hip_bfloat16* Brow0 = B + (long)(nb + r0s) * ldb + c0s;
  const __hip_bfloat16* Brow1 = B + (long)(nb + r1s) * ldb + c1s;

  const int arow = wm + (l & 15);
  const int ldsA = arow * 32 + ((((l >> 4) ^ ((arow >> 1) & 3))) << 3);
  const int brow = wn + (l & 15);
  const int ldsB = brow * 32 + ((((l >> 4) ^ ((brow >> 1) & 3))) << 3);

  auto stage = [&](int k0, int buf) {
    __builtin_amdgcn_global_load_lds(GBL_AS(Arow0 + k0),
        LDS_AS(&As[buf][cb0 * 8]), 16, 0, 0);
    __builtin_amdgcn_global_load_lds(GBL_AS(Brow0 + k0),
        LDS_AS(&Bs[buf][cb0 * 8]), 16, 0, 0);
    __builtin_amdgcn_global_load_lds(GBL_AS(Arow1 + k0),
        LDS_AS(&As[buf][cb1 * 8]), 16, 0, 0);
    __builtin_amdgcn_global_load_lds(GBL_AS(Brow1 + k0),
        LDS_AS(&Bs[buf][cb1 * 8]), 16, 0, 0);
  };
  stage(0, 0);
  if (32 < kend) stage(32, 1);
  int bi = 0;
  for (int k0 = 0; k0 < kend; k0 += 32) {
    if (k0 + 32 < kend) WAIT_VM4(); else WAIT_VM0();
    __builtin_amdgcn_s_barrier();
    if (k0 + 64 < kend) stage(k0 + 64, bi == 0 ? 2 : bi - 1);
    v8bf af[4], bfr[4];
#pragma unroll
    for (int i = 0; i < 4; ++i) {
      af[i]  = *(const v8bf*)(&As[bi][ldsA + i * 512]);
      bfr[i] = *(const v8bf*)(&Bs[bi][ldsB + i * 512]);
    }
#pragma unroll
    for (int i = 0; i < 4; ++i)
#pragma unroll
      for (int jj = 0; jj < 4; ++jj)
        acc[i][jj] = __builtin_amdgcn_mfma_f32_16x16x32_bf16(af[i], bfr[jj], acc[i][jj], 0, 0, 0);
    bi = (bi == 2) ? 0 : bi + 1;
  }

  // epilogue: divide by rowsum, fp32 direct stores
  float* Cz = C + (long)z * sCb;
  const float* srow = sums + z * 2048;
  const int col0 = nb + wn + (l & 15);
  const int row0 = mb + wm + ((l >> 4) << 2);
#pragma unroll
  for (int i = 0; i < 4; ++i)
#pragma unroll
    for (int r = 0; r < 4; ++r) {
      const int mr = row0 + i * 16 + r;
      const float sc = 1.0f / srow[mr];
      const long ro = (long)mr * ldc;
#pragma unroll
      for (int jj = 0; jj < 4; ++jj)
        Cz[ro + col0 + jj * 16] = acc[i][jj][r] * sc;
    }
}

// ---------------- launch ----------------
extern "C" void kernel_launch(void* const* d_in, const int* in_sizes, int n_in,
                              void* d_out, int out_size, void* d_ws, size_t ws_size,
                              hipStream_t stream) {
  const float* x  = (const float*)d_in[0];
  const float* Wq = (const float*)d_in[1];
  const float* Wk = (const float*)d_in[2];
  const float* Wv = (const float*)d_in[3];
  float* out = (float*)d_out;
  char* ws = (char*)d_ws;

  // ws layout (bytes):
  //   qkv bf16 [3][8192][1024]   @ 0          (48 MB; v-slice unused)
  //   vT  bf16 [4][1024][2048]   @ 50331648   (16 MB)
  //   xb  bf16 [8192][1024]      @ 67108864   (16 MB, dead after proj)
  //   Wb  bf16 [3][1024][1024]   @ 83886080   ( 6 MB, dead after proj)
  //   P   bf16 [4][2048][2048]   @ 67108864   (32 MB, overlaps dead xb/Wb)
  //   sums fp32 [8192]           @ 100663296  (32 KB)
  __hip_bfloat16* qkv = (__hip_bfloat16*)ws;
  __hip_bfloat16* vT  = (__hip_bfloat16*)(ws + 50331648);
  __hip_bfloat16* xb  = (__hip_bfloat16*)(ws + 67108864);
  __hip_bfloat16* Wb  = (__hip_bfloat16*)(ws + 83886080);
  __hip_bfloat16* P   = (__hip_bfloat16*)(ws + 67108864);
  float* sums         = (float*)(ws + 100663296);

  hipMemsetAsync(sums, 0, 8192 * sizeof(float), stream);

  cast_f32_bf16<<<8192, 256, 0, stream>>>(x, xb, 8388608);
  cast_w3<<<3072, 256, 0, stream>>>(Wq, Wk, Wv, Wb);

  // qkv projections; z==2 (V) written transposed into vT by the epilogue
  gemm_proj<<<dim3(24, 32, 1), 256, 0, stream>>>(
      xb, 1024, Wb, 1048576L, 1024, qkv, 8388608L, 1024, 1.0f, vT);

  // P = exp((q@k^T)/32) causal, bf16, fused row-sums; XCD-chunked schedule
  gemm_score<<<dim3(544, 1, 1), 256, 0, stream>>>(
      qkv, 2097152L, qkv + 8388608, 2097152L,
      P, 4194304L, 0.03125f, sums);

  // out = (P @ vT^T) / rowsum; XCD-chunked schedule, m descending
  gemm_pv<<<dim3(512, 1, 1), 256, 0, stream>>>(
      P, 4194304L, 2048, vT, 2097152L, 2048,
      out, 2097152L, 1024, sums);
}